// Round 1
// baseline (5808.627 us; speedup 1.0000x reference)
//
#include <hip/hip_runtime.h>
#include <stdint.h>
#include <stddef.h>

#define TT 1024
#define BB 64
#define HH 1024
#define II 1024

typedef __attribute__((ext_vector_type(8))) short s16x8;
typedef __attribute__((ext_vector_type(4))) float f32x4;

static __device__ __forceinline__ unsigned short f2bf(float f) {
    union { float f; unsigned int u; } v; v.f = f;
    return (unsigned short)((v.u + 0x7fffu + ((v.u >> 16) & 1u)) >> 16);
}

static __device__ __forceinline__ s16x8 pack8(float4 a, float4 b) {
    s16x8 v;
    v[0] = (short)f2bf(a.x); v[1] = (short)f2bf(a.y);
    v[2] = (short)f2bf(a.z); v[3] = (short)f2bf(a.w);
    v[4] = (short)f2bf(b.x); v[5] = (short)f2bf(b.y);
    v[6] = (short)f2bf(b.z); v[7] = (short)f2bf(b.w);
    return v;
}

static __device__ __forceinline__ f32x4 zero4() {
    f32x4 v = {0.f, 0.f, 0.f, 0.f};
    return v;
}

// ---------------------------------------------------------------------------
// Kernel 0: zero the barrier counters in workspace (graph-capture-safe init).
// ---------------------------------------------------------------------------
__global__ void init_cnt(unsigned int* cnt) {
    cnt[threadIdx.x] = 0u;
}

// ---------------------------------------------------------------------------
// Kernel 1: xw = x @ W_ih^T + b_ih + b_hh  ->  written into d_out states area
// [B*T, I] x [H, I] -> [B*T, H], bf16 inputs (converted in staging), fp32 out.
// 128x128 tile, BK=64, 4 waves (2x2), 16x16x32 MFMA, XOR-swizzled LDS.
// ---------------------------------------------------------------------------
__global__ __launch_bounds__(256, 2) void xw_gemm(
    const float* __restrict__ X,
    const float* __restrict__ Wih,
    const float* __restrict__ bih,
    const float* __restrict__ bhh,
    float* __restrict__ out)
{
    __shared__ unsigned short As[128 * 64];   // 16 KiB, swizzled bf16
    __shared__ unsigned short Bs[128 * 64];   // 16 KiB, swizzled bf16

    const int tid  = threadIdx.x;
    const int lane = tid & 63;
    const int wid  = tid >> 6;
    const int bm = blockIdx.x >> 3;
    const int bn = blockIdx.x & 7;
    const size_t m0 = (size_t)bm * 128;
    const int n0 = bn * 128;
    const int wm = (wid >> 1) * 64;
    const int wn = (wid & 1) * 64;

    f32x4 acc[4][4];
#pragma unroll
    for (int i = 0; i < 4; ++i)
#pragma unroll
        for (int j = 0; j < 4; ++j) acc[i][j] = zero4();

    const int srow  = tid >> 1;   // 0..127: row of both A and B tiles
    const int shalf = tid & 1;    // half-row of 32 floats
    const float* xp = X   + (m0 + srow) * (size_t)II + shalf * 32;
    const float* wp = Wih + (size_t)(n0 + srow) * II + shalf * 32;

    for (int kt = 0; kt < II / 64; ++kt) {
        // ---- stage: fp32 global -> bf16 swizzled LDS ----
#pragma unroll
        for (int i = 0; i < 4; ++i) {
            float4 a0 = *(const float4*)(xp + i * 8);
            float4 a1 = *(const float4*)(xp + i * 8 + 4);
            float4 b0 = *(const float4*)(wp + i * 8);
            float4 b1 = *(const float4*)(wp + i * 8 + 4);
            const int c = shalf * 4 + i;              // chunk 0..7 (16B each)
            const int cw = (c ^ (srow & 7)) << 3;
            *(s16x8*)&As[srow * 64 + cw] = pack8(a0, a1);
            *(s16x8*)&Bs[srow * 64 + cw] = pack8(b0, b1);
        }
        __syncthreads();

        // ---- compute: 2 k-subtiles of 32 ----
#pragma unroll
        for (int kk = 0; kk < 2; ++kk) {
            s16x8 af[4], bf[4];
            const int cs = kk * 4 + (lane >> 4);
#pragma unroll
            for (int mi = 0; mi < 4; ++mi) {
                const int r = wm + mi * 16 + (lane & 15);
                af[mi] = *(const s16x8*)&As[r * 64 + ((cs ^ (r & 7)) << 3)];
            }
#pragma unroll
            for (int ni = 0; ni < 4; ++ni) {
                const int r = wn + ni * 16 + (lane & 15);
                bf[ni] = *(const s16x8*)&Bs[r * 64 + ((cs ^ (r & 7)) << 3)];
            }
#pragma unroll
            for (int mi = 0; mi < 4; ++mi)
#pragma unroll
                for (int ni = 0; ni < 4; ++ni)
                    acc[mi][ni] = __builtin_amdgcn_mfma_f32_16x16x32_bf16(
                        af[mi], bf[ni], acc[mi][ni], 0, 0, 0);
        }
        __syncthreads();
        xp += 64; wp += 64;
    }

    // ---- epilogue: + (b_ih + b_hh), store fp32 ----
#pragma unroll
    for (int ni = 0; ni < 4; ++ni) {
        const int col = n0 + wn + ni * 16 + (lane & 15);
        const float bias = bih[col] + bhh[col];
#pragma unroll
        for (int mi = 0; mi < 4; ++mi) {
            const size_t row = m0 + wm + mi * 16 + ((lane >> 4) << 2);
#pragma unroll
            for (int r = 0; r < 4; ++r)
                out[(row + r) * (size_t)HH + col] = acc[mi][ni][r] + bias;
        }
    }
}

// ---------------------------------------------------------------------------
// Per-batch-group barrier: 16 WGs, monotone counter, agent scope.
// ---------------------------------------------------------------------------
static __device__ __forceinline__ void group_barrier(unsigned int* c, unsigned int target) {
    __syncthreads();
    if (threadIdx.x == 0) {
        __hip_atomic_fetch_add(c, 1u, __ATOMIC_RELEASE, __HIP_MEMORY_SCOPE_AGENT);
        while (__hip_atomic_load(c, __ATOMIC_RELAXED, __HIP_MEMORY_SCOPE_AGENT) < target)
            __builtin_amdgcn_s_sleep(1);
        (void)__hip_atomic_load(c, __ATOMIC_ACQUIRE, __HIP_MEMORY_SCOPE_AGENT);
    }
    __syncthreads();
}

// ---------------------------------------------------------------------------
// Kernel 2: persistent scan. Grid = 64 WGs = 4 batch-groups x 16 j-slices.
// Each WG: W_hh rows [j0, j0+64) pinned in LDS (bf16, XOR-swizzled, 128 KiB).
// Per step: stage hr tile (16b x 1024k, 32 KiB) from global ring -> LDS,
// 32x (2 ds_read_b128 + mfma_16x16x32_bf16) per wave, tanh epilogue in-place
// on d_out, write hr_{t+1} = 0.5(h_t + h_{t-1}) bf16 to ring, group barrier.
// ---------------------------------------------------------------------------
__global__ __launch_bounds__(256, 1) void rnn_scan(
    const float* __restrict__ Whh,
    float* __restrict__ out,            // [B,T,H] fp32 (xw in, states out) + final [B,H]
    unsigned short* __restrict__ ring,  // 2 slots x [B,H] bf16
    unsigned int* __restrict__ cnt)     // 4 counters, 128B stride
{
    __shared__ unsigned short Wl[64 * 1024];  // 128 KiB
    __shared__ unsigned short Hl[16 * 1024];  //  32 KiB

    const int tid  = threadIdx.x;
    const int lane = tid & 63;
    const int wid  = tid >> 6;
    const int jg = blockIdx.x & 15;
    const int bg = blockIdx.x >> 4;
    const int j0 = jg * 64, b0 = bg * 16;

    // ---- one-time: W_hh slice -> swizzled bf16 LDS ----
    {
        const int jr = tid >> 2;     // 0..63
        const int q  = tid & 3;      // k quarter
        const float* src = Whh + (size_t)(j0 + jr) * HH + q * 256;
#pragma unroll
        for (int i = 0; i < 32; ++i) {
            float4 p0 = *(const float4*)(src + i * 8);
            float4 p1 = *(const float4*)(src + i * 8 + 4);
            const int c = q * 32 + i;           // chunk 0..127
            *(s16x8*)&Wl[jr * 1024 + ((c ^ (jr & 7)) << 3)] = pack8(p0, p1);
        }
    }
    // (Wl visibility covered by the syncthreads inside the first group_barrier)

    const int jcol  = lane & 15;
    const int brow  = (lane >> 4) << 2;     // 0,4,8,12
    const int myj   = j0 + wid * 16 + jcol; // global output feature
    const int jr_my = wid * 16 + jcol;      // Wl row for B-fragment
    const int arow  = lane & 15;            // Hl row for A-fragment
    unsigned int* mycnt = cnt + bg * 32;

    float hprev[4];

    // ---- t = 0: h = tanh(xw), no recurrent term ----
#pragma unroll
    for (int r = 0; r < 4; ++r) {
        const size_t idx = ((size_t)(b0 + brow + r) * TT) * HH + myj;
        const float h = tanhf(out[idx]);
        out[idx] = h;
        hprev[r] = h;
        // hr_1 = 0.5*(h_0 + h_{-1}=0) -> slot 1
        ring[(size_t)BB * HH + (b0 + brow + r) * HH + myj] = f2bf(0.5f * h);
    }
    group_barrier(mycnt, 16u);

#pragma unroll 1
    for (int t = 1; t < TT; ++t) {
        // ---- stage hr (slot t&1) rows b0..b0+15 into swizzled LDS ----
        {
            const int br = tid >> 4;     // 0..15
            const int c0 = tid & 15;     // chunk start
            const unsigned short* src =
                ring + (size_t)(t & 1) * BB * HH + (size_t)(b0 + br) * HH;
#pragma unroll
            for (int i = 0; i < 8; ++i) {
                const int c = c0 + (i << 4);
                const s16x8 v = *(const s16x8*)(src + (c << 3));
                *(s16x8*)&Hl[br * 1024 + ((c ^ (br & 7)) << 3)] = v;
            }
        }
        __syncthreads();

        // xw loads issue early, latency hidden under the MFMA loop
        float xw[4];
        size_t xidx[4];
#pragma unroll
        for (int r = 0; r < 4; ++r) {
            xidx[r] = ((size_t)(b0 + brow + r) * TT + t) * HH + myj;
            xw[r] = out[xidx[r]];
        }

        f32x4 acc = zero4();
#pragma unroll
        for (int ki = 0; ki < 32; ++ki) {
            const int cs = (ki << 2) + (lane >> 4);
            const s16x8 a = *(const s16x8*)&Hl[arow * 1024 + ((cs ^ (arow & 7)) << 3)];
            const s16x8 b = *(const s16x8*)&Wl[jr_my * 1024 + ((cs ^ (jr_my & 7)) << 3)];
            acc = __builtin_amdgcn_mfma_f32_16x16x32_bf16(a, b, acc, 0, 0, 0);
        }

        unsigned short* rout = ring + (size_t)((t + 1) & 1) * BB * HH;
#pragma unroll
        for (int r = 0; r < 4; ++r) {
            const float h = tanhf(acc[r] + xw[r]);
            out[xidx[r]] = h;
            if (t == TT - 1)
                out[(size_t)BB * TT * HH + (size_t)(b0 + brow + r) * HH + myj] = h;
            rout[(b0 + brow + r) * HH + myj] = f2bf(0.5f * (h + hprev[r]));
            hprev[r] = h;
        }

        if (t < TT - 1) group_barrier(mycnt, (unsigned)(t + 1) * 16u);
    }
}

// ---------------------------------------------------------------------------
extern "C" void kernel_launch(void* const* d_in, const int* in_sizes, int n_in,
                              void* d_out, int out_size, void* d_ws, size_t ws_size,
                              hipStream_t stream)
{
    const float* X   = (const float*)d_in[0];
    const float* Wih = (const float*)d_in[1];
    const float* Whh = (const float*)d_in[2];
    const float* bih = (const float*)d_in[3];
    const float* bhh = (const float*)d_in[4];
    float* out = (float*)d_out;

    unsigned int*   cnt  = (unsigned int*)d_ws;
    unsigned short* ring = (unsigned short*)((char*)d_ws + 4096);

    init_cnt<<<dim3(1), dim3(128), 0, stream>>>(cnt);
    xw_gemm<<<dim3(4096), dim3(256), 0, stream>>>(X, Wih, bih, bhh, out);
    rnn_scan<<<dim3(64), dim3(256), 0, stream>>>(Whh, out, ring, cnt);
}